// Round 2
// baseline (195.589 us; speedup 1.0000x reference)
//
#include <hip/hip_runtime.h>
#include <hip/hip_bf16.h>

#define BSZ 4096
#define NSZ 8192
#define DD  128
#define TILE 128
#define INV_TAU 10.0f
#define NG 16    // col-tile groups (grid.x)
#define TPG 4    // tiles per group

typedef __attribute__((ext_vector_type(8))) short bf16x8;
typedef __attribute__((ext_vector_type(4))) float f32x4;

// ---------------- Kernel 1: normalize rows of reps=[zjs; zis] -> bf16 ----------------
// 1 wave per row, 4 rows per 256-thread block.
__global__ __launch_bounds__(256)
void norm_kernel(const float* __restrict__ zis,
                 const float* __restrict__ zjs,
                 __hip_bfloat16* __restrict__ rn) {
    const int row  = blockIdx.x * 4 + (threadIdx.x >> 6);
    const int lane = threadIdx.x & 63;
    const float* src = (row < BSZ) ? (zjs + (size_t)row * DD)
                                   : (zis + (size_t)(row - BSZ) * DD);
    float2 v = *(const float2*)(src + lane * 2);
    float ss = v.x * v.x + v.y * v.y;
    #pragma unroll
    for (int off = 32; off; off >>= 1) ss += __shfl_xor(ss, off);
    float inv = 1.0f / fmaxf(sqrtf(ss), 1e-8f);
    __hip_bfloat16 a = __float2bfloat16(v.x * inv);
    __hip_bfloat16 b = __float2bfloat16(v.y * inv);
    ushort2 pk;
    pk.x = *(const ushort*)&a;
    pk.y = *(const ushort*)&b;
    *(ushort2*)(rn + (size_t)row * DD + lane * 2) = pk;
}

// ---------------- Kernel 2: fused sim GEMM + exp + per-row sum ----------------
// grid (NG, 64): blockIdx.y = bi (row tile of 128), blockIdx.x = g (group of
// TPG consecutive col tiles). 512 threads = 8 waves; wave w owns rows
// [w*16, w*16+16) of the tile. A kept in registers; B staged in LDS via
// registers with prefetch of the next tile overlapping compute.
__global__ __launch_bounds__(512, 4)
void sim_lse_kernel(const __hip_bfloat16* __restrict__ rn,
                    float* __restrict__ sumexp,
                    float* __restrict__ pos) {
    __shared__ ushort Bt[TILE * DD];   // 32 KB, XOR-swizzled

    const int bi  = blockIdx.y;
    const int g   = blockIdx.x;
    const int tid = threadIdx.x;
    const int wid  = tid >> 6;
    const int lane = tid & 63;
    const int l15  = lane & 15;
    const int kg   = lane >> 4;        // 0..3

    const int rowbase = bi * TILE + wid * 16;

    // ---- A fragments: 16 rows per wave, held in registers for all tiles ----
    const char* abase = (const char*)rn + (size_t)(rowbase + l15) * 256;
    bf16x8 af[4];
    #pragma unroll
    for (int kk = 0; kk < 4; ++kk)
        af[kk] = *(const bf16x8*)(abase + kk * 64 + kg * 16);

    float psum[4] = {0.f, 0.f, 0.f, 0.f};

    // ---- prefetch B tile 0 into registers ----
    uint4 st[4];
    {
        const uint4* bsrc = (const uint4*)((const char*)rn + (size_t)(g * TPG) * TILE * 256);
        #pragma unroll
        for (int it = 0; it < 4; ++it) st[it] = bsrc[tid + it * 512];
    }

    for (int t = 0; t < TPG; ++t) {
        const int bj = g * TPG + t;

        // write staged regs -> LDS (swizzled: chunk ^= row&7, 16B granular)
        uint4* bdst = (uint4*)Bt;
        #pragma unroll
        for (int it = 0; it < 4; ++it) {
            int c = tid + it * 512;
            int row = c >> 4;
            bdst[c ^ (row & 7)] = st[it];
        }
        __syncthreads();

        // prefetch next tile (overlaps with MFMA below)
        if (t + 1 < TPG) {
            const uint4* bsrc = (const uint4*)((const char*)rn + (size_t)(bj + 1) * TILE * 256);
            #pragma unroll
            for (int it = 0; it < 4; ++it) st[it] = bsrc[tid + it * 512];
        }

        // ---- MFMA: 16 rows x 128 cols, K=128 ----
        f32x4 acc[8] = {};
        const char* Bb = (const char*)Bt;
        #pragma unroll
        for (int kk = 0; kk < 4; ++kk) {
            const int kb = kk * 64 + kg * 16;
            bf16x8 bfr[8];
            #pragma unroll
            for (int cf = 0; cf < 8; ++cf) {
                int cR = cf * 16 + l15;
                int o = cR * 256 + kb;
                bfr[cf] = *(const bf16x8*)(Bb + (o ^ ((cR & 7) << 4)));
            }
            #pragma unroll
            for (int cf = 0; cf < 8; ++cf)
                acc[cf] = __builtin_amdgcn_mfma_f32_16x16x32_bf16(
                    af[kk], bfr[cf], acc[cf], 0, 0, 0);
        }

        // ---- epilogue for this tile: pos capture + exp + psum accumulate ----
        const int colbase = bj * TILE;
        const bool diag = (bj == bi);
        const bool posb = (bj == ((bi + 32) & 63));
        #pragma unroll
        for (int cf = 0; cf < 8; ++cf) {
            #pragma unroll
            for (int reg = 0; reg < 4; ++reg) {
                float s = acc[cf][reg];
                int r = rowbase + kg * 4 + reg;
                int c = colbase + cf * 16 + l15;
                if (posb && ((c - r) == BSZ || (r - c) == BSZ)) pos[r] = s;
                float p = (diag && r == c) ? 0.0f : __expf(s * INV_TAU);
                psum[reg] += p;
            }
        }
        __syncthreads();   // protect Bt before next iteration's writes
    }

    // ---- final: reduce psum over the 16 lanes of each row-group, one atomic ----
    #pragma unroll
    for (int reg = 0; reg < 4; ++reg) {
        float v = psum[reg];
        v += __shfl_xor(v, 1);
        v += __shfl_xor(v, 2);
        v += __shfl_xor(v, 4);
        v += __shfl_xor(v, 8);
        if (l15 == 0)
            atomicAdd(&sumexp[rowbase + kg * 4 + reg], v);
    }
}

// ---------------- Kernel 3: final scalar reduction ----------------
__global__ __launch_bounds__(1024)
void reduce_kernel(const float* __restrict__ sumexp,
                   const float* __restrict__ pos,
                   float* __restrict__ out) {
    int tid = threadIdx.x;  // 1024
    float ce = 0.f, pt = 0.f;
    for (int i = tid; i < NSZ; i += 1024) {
        float se = sumexp[i];
        float p  = pos[i];
        ce += __logf(se) - p * INV_TAU;
        pt += __expf(p * INV_TAU) / se;
    }
    #pragma unroll
    for (int off = 32; off; off >>= 1) {
        ce += __shfl_xor(ce, off);
        pt += __shfl_xor(pt, off);
    }
    __shared__ float lce[16], lpt[16];
    if ((tid & 63) == 0) { lce[tid >> 6] = ce; lpt[tid >> 6] = pt; }
    __syncthreads();
    if (tid == 0) {
        float CE = 0.f, PT = 0.f;
        #pragma unroll
        for (int w = 0; w < 16; ++w) { CE += lce[w]; PT += lpt[w]; }
        float loss = CE / (float)NSZ + 1.0f
                   - PT * ((float)BSZ / ((float)NSZ * (float)(NSZ - 1)));
        out[0] = loss;
    }
}

extern "C" void kernel_launch(void* const* d_in, const int* in_sizes, int n_in,
                              void* d_out, int out_size, void* d_ws, size_t ws_size,
                              hipStream_t stream) {
    const float* zis = (const float*)d_in[0];
    const float* zjs = (const float*)d_in[1];
    float* out = (float*)d_out;

    char* ws = (char*)d_ws;
    __hip_bfloat16* rn = (__hip_bfloat16*)ws;                 // 2 MB
    float* sumexp = (float*)(ws + 2 * 1024 * 1024);           // 32 KB
    float* pos    = (float*)(ws + 2 * 1024 * 1024 + 32768);   // 32 KB

    hipMemsetAsync(sumexp, 0, NSZ * sizeof(float), stream);

    norm_kernel<<<NSZ / 4, 256, 0, stream>>>(zis, zjs, rn);

    dim3 grid(NG, 64);
    sim_lse_kernel<<<grid, 512, 0, stream>>>(rn, sumexp, pos);

    reduce_kernel<<<1, 1024, 0, stream>>>(sumexp, pos, out);
}

// Round 3
// 53.681 us; speedup vs baseline: 3.6436x; 3.6436x over previous
//
#include <hip/hip_runtime.h>
#include <hip/hip_bf16.h>

#define BSZ 4096
#define NSZ 8192
#define DD  128
#define TILE 128
#define INV_TAU 10.0f

typedef __attribute__((ext_vector_type(8))) short bf16x8;
typedef __attribute__((ext_vector_type(4))) float f32x4;

typedef __attribute__((address_space(3))) unsigned int lds_u32;
typedef const __attribute__((address_space(1))) unsigned int glb_u32;

// ---------------- Kernel 1: normalize rows of reps=[zjs; zis] -> bf16 ----------------
__global__ __launch_bounds__(256)
void norm_kernel(const float* __restrict__ zis,
                 const float* __restrict__ zjs,
                 __hip_bfloat16* __restrict__ rn) {
    const int row  = blockIdx.x * 4 + (threadIdx.x >> 6);
    const int lane = threadIdx.x & 63;
    const float* src = (row < BSZ) ? (zjs + (size_t)row * DD)
                                   : (zis + (size_t)(row - BSZ) * DD);
    float2 v = *(const float2*)(src + lane * 2);
    float ss = v.x * v.x + v.y * v.y;
    #pragma unroll
    for (int off = 32; off; off >>= 1) ss += __shfl_xor(ss, off);
    float inv = 1.0f / fmaxf(sqrtf(ss), 1e-8f);
    __hip_bfloat16 a = __float2bfloat16(v.x * inv);
    __hip_bfloat16 b = __float2bfloat16(v.y * inv);
    ushort2 pk;
    pk.x = *(const ushort*)&a;
    pk.y = *(const ushort*)&b;
    *(ushort2*)(rn + (size_t)row * DD + lane * 2) = pk;
}

// ---------------- Kernel 2: triangular fused sim GEMM + exp + row/col sums ----------
// grid (64, 33): i = blockIdx.x, d = blockIdx.y; bi=i, bj=(i+d)&63.
// d==32 only valid for i<32 (others exit). Covers each unordered tile pair once.
// 256 threads = 4 waves; wave w owns A-rows [w*32, w*32+32).
// A (bi-tile rows) in registers; B (bj-tile) in LDS, XOR-swizzled, staged via
// global_load_lds with pre-swizzled per-lane global source.
__global__ __launch_bounds__(256)
void sim_lse_kernel(const __hip_bfloat16* __restrict__ rn,
                    float* __restrict__ sumexp,
                    float* __restrict__ pos) {
    __shared__ ushort Bt[TILE * DD];   // 32 KB

    const int i = blockIdx.x;
    const int d = blockIdx.y;
    if (d == 32 && i >= 32) return;
    const int bi = i;
    const int bj = (i + d) & 63;

    const int tid  = threadIdx.x;
    const int wid  = tid >> 6;
    const int lane = tid & 63;
    const int l15  = lane & 15;
    const int kg   = lane >> 4;        // 0..3

    // ---- stage B tile: LDS linear dest, pre-swizzled global source ----
    {
        const char* gbase = (const char*)rn + (size_t)bj * TILE * 256;
        #pragma unroll
        for (int j = 0; j < 8; ++j) {
            int cs  = (wid * 8 + j) * 64 + lane;     // dest chunk (16B units)
            int gsc = cs ^ ((cs >> 4) & 7);          // swizzled source chunk
            const char* gp = gbase + (size_t)gsc * 16;
            ushort* lp = Bt + (wid * 8 + j) * 512;   // wave-uniform base
            __builtin_amdgcn_global_load_lds((glb_u32*)gp, (lds_u32*)lp, 16, 0, 0);
        }
    }

    // ---- A fragments: 32 rows per wave, in registers ----
    const int rowloc = wid * 32;
    const char* abase = (const char*)rn + (size_t)(bi * TILE + rowloc + l15) * 256;
    bf16x8 af[2][4];
    #pragma unroll
    for (int mt = 0; mt < 2; ++mt)
        #pragma unroll
        for (int kk = 0; kk < 4; ++kk)
            af[mt][kk] = *(const bf16x8*)(abase + mt * 16 * 256 + kk * 64 + kg * 16);

    __syncthreads();   // drains vmcnt(0): staging + af complete

    // ---- MFMA: 32 rows x 128 cols, K=128 ----
    f32x4 acc[2][8] = {};
    const char* Bb = (const char*)Bt;
    #pragma unroll
    for (int kk = 0; kk < 4; ++kk) {
        const int kb = kk * 64 + kg * 16;
        #pragma unroll
        for (int h = 0; h < 2; ++h) {
            bf16x8 bfr[4];
            #pragma unroll
            for (int f = 0; f < 4; ++f) {
                int cR = (h * 4 + f) * 16 + l15;
                int o = cR * 256 + kb;
                bfr[f] = *(const bf16x8*)(Bb + (o ^ ((cR & 7) << 4)));
            }
            #pragma unroll
            for (int mt = 0; mt < 2; ++mt)
                #pragma unroll
                for (int f = 0; f < 4; ++f)
                    acc[mt][h * 4 + f] = __builtin_amdgcn_mfma_f32_16x16x32_bf16(
                        af[mt][kk], bfr[f], acc[mt][h * 4 + f], 0, 0, 0);
        }
    }

    // ---- epilogue: exp once, accumulate row sums (bi side) + col sums (bj side) ----
    const int rowg0 = bi * TILE + rowloc;      // + mt*16 + kg*4 + reg
    const int colg0 = bj * TILE;               // + cf*16 + l15
    const bool diag = (d == 0);
    const bool posb = ((bj - bi) == 32);

    float rsum[2][4] = {};
    float csum[8] = {};
    #pragma unroll
    for (int mt = 0; mt < 2; ++mt) {
        #pragma unroll
        for (int cf = 0; cf < 8; ++cf) {
            #pragma unroll
            for (int reg = 0; reg < 4; ++reg) {
                float s = acc[mt][cf][reg];
                int r = rowg0 + mt * 16 + kg * 4 + reg;
                int c = colg0 + cf * 16 + l15;
                if (posb && (c - r) == BSZ) { pos[r] = s; pos[c] = s; }
                float p = (diag && r == c) ? 0.0f : __expf(s * INV_TAU);
                rsum[mt][reg] += p;
                csum[cf] += p;
            }
        }
    }

    // row sums: reduce across the 16 l15-lanes of each (kg) row group
    #pragma unroll
    for (int mt = 0; mt < 2; ++mt) {
        #pragma unroll
        for (int reg = 0; reg < 4; ++reg) {
            float v = rsum[mt][reg];
            v += __shfl_xor(v, 1);
            v += __shfl_xor(v, 2);
            v += __shfl_xor(v, 4);
            v += __shfl_xor(v, 8);
            if (l15 == 0)
                atomicAdd(&sumexp[rowg0 + mt * 16 + kg * 4 + reg], v);
        }
    }

    // col sums (transpose contribution): reduce across kg groups; skip on diagonal
    if (!diag) {
        #pragma unroll
        for (int cf = 0; cf < 8; ++cf) {
            float v = csum[cf];
            v += __shfl_xor(v, 16);
            v += __shfl_xor(v, 32);
            if (kg == 0)
                atomicAdd(&sumexp[colg0 + cf * 16 + l15], v);
        }
    }
}

// ---------------- Kernel 3: final scalar reduction ----------------
__global__ __launch_bounds__(1024)
void reduce_kernel(const float* __restrict__ sumexp,
                   const float* __restrict__ pos,
                   float* __restrict__ out) {
    int tid = threadIdx.x;  // 1024; 8 elements each, 8192 total
    int base = tid * 8;
    float ce = 0.f, pt = 0.f;
    #pragma unroll
    for (int h = 0; h < 2; ++h) {
        float4 se4 = *(const float4*)(sumexp + base + h * 4);
        float4 p4  = *(const float4*)(pos + base + h * 4);
        const float* se = (const float*)&se4;
        const float* pp = (const float*)&p4;
        #pragma unroll
        for (int q = 0; q < 4; ++q) {
            ce += __logf(se[q]) - pp[q] * INV_TAU;
            pt += __expf(pp[q] * INV_TAU) / se[q];
        }
    }
    #pragma unroll
    for (int off = 32; off; off >>= 1) {
        ce += __shfl_xor(ce, off);
        pt += __shfl_xor(pt, off);
    }
    __shared__ float lce[16], lpt[16];
    if ((tid & 63) == 0) { lce[tid >> 6] = ce; lpt[tid >> 6] = pt; }
    __syncthreads();
    if (tid == 0) {
        float CE = 0.f, PT = 0.f;
        #pragma unroll
        for (int w = 0; w < 16; ++w) { CE += lce[w]; PT += lpt[w]; }
        float loss = CE / (float)NSZ + 1.0f
                   - PT * ((float)BSZ / ((float)NSZ * (float)(NSZ - 1)));
        out[0] = loss;
    }
}

extern "C" void kernel_launch(void* const* d_in, const int* in_sizes, int n_in,
                              void* d_out, int out_size, void* d_ws, size_t ws_size,
                              hipStream_t stream) {
    const float* zis = (const float*)d_in[0];
    const float* zjs = (const float*)d_in[1];
    float* out = (float*)d_out;

    char* ws = (char*)d_ws;
    __hip_bfloat16* rn = (__hip_bfloat16*)ws;                 // 2 MB
    float* sumexp = (float*)(ws + 2 * 1024 * 1024);           // 32 KB
    float* pos    = (float*)(ws + 2 * 1024 * 1024 + 32768);   // 32 KB

    hipMemsetAsync(sumexp, 0, NSZ * sizeof(float), stream);

    norm_kernel<<<NSZ / 4, 256, 0, stream>>>(zis, zjs, rn);

    dim3 grid(64, 33);
    sim_lse_kernel<<<grid, 256, 0, stream>>>(rn, sumexp, pos);

    reduce_kernel<<<1, 1024, 0, stream>>>(sumexp, pos, out);
}

// Round 4
// 43.545 us; speedup vs baseline: 4.4916x; 1.2328x over previous
//
#include <hip/hip_runtime.h>
#include <hip/hip_bf16.h>

#define BSZ 4096
#define NSZ 8192
#define DD  128
#define TILE 128
#define INV_TAU 10.0f
#define GROUPS 8
#define TPB 8     // col-tiles per block

typedef __attribute__((ext_vector_type(8))) short bf16x8;
typedef __attribute__((ext_vector_type(4))) float f32x4;

typedef __attribute__((address_space(3))) unsigned int lds_u32;
typedef const __attribute__((address_space(1))) unsigned int glb_u32;

// ---------------- Kernel 1: normalize rows of reps=[zjs; zis] -> bf16 ----------------
__global__ __launch_bounds__(256)
void norm_kernel(const float* __restrict__ zis,
                 const float* __restrict__ zjs,
                 __hip_bfloat16* __restrict__ rn) {
    const int row  = blockIdx.x * 4 + (threadIdx.x >> 6);
    const int lane = threadIdx.x & 63;
    const float* src = (row < BSZ) ? (zjs + (size_t)row * DD)
                                   : (zis + (size_t)(row - BSZ) * DD);
    float2 v = *(const float2*)(src + lane * 2);
    float ss = v.x * v.x + v.y * v.y;
    #pragma unroll
    for (int off = 32; off; off >>= 1) ss += __shfl_xor(ss, off);
    float inv = 1.0f / fmaxf(sqrtf(ss), 1e-8f);
    __hip_bfloat16 a = __float2bfloat16(v.x * inv);
    __hip_bfloat16 b = __float2bfloat16(v.y * inv);
    ushort2 pk;
    pk.x = *(const ushort*)&a;
    pk.y = *(const ushort*)&b;
    *(ushort2*)(rn + (size_t)row * DD + lane * 2) = pk;
}

// ---------------- Kernel 2: deep-loop fused sim GEMM + exp + row sums ----------------
// grid (GROUPS, 64): bi = blockIdx.y (row tile), g = blockIdx.x; block loops over
// bj = g*TPB .. g*TPB+TPB-1 with double-buffered LDS B staging (global_load_lds,
// pre-swizzled source). 256 threads = 4 waves in a 2x2 grid; each wave owns
// 64 rows x 64 cols. A-frags in registers for the whole block. Row-sums of
// exp(s/tau) accumulate in registers across all TPB tiles; one atomic per row.
__global__ __launch_bounds__(256, 2)
void sim_lse_kernel(const __hip_bfloat16* __restrict__ rn,
                    float* __restrict__ sumexp,
                    float* __restrict__ pos) {
    __shared__ ushort Bt[2][TILE * DD];   // 2 x 32 KB

    const int g   = blockIdx.x;
    const int bi  = blockIdx.y;
    const int tid = threadIdx.x;
    const int wid  = tid >> 6;
    const int lane = tid & 63;
    const int l15  = lane & 15;
    const int kg   = lane >> 4;        // 0..3
    const int wm   = wid >> 1;         // 0..1 row half
    const int wn   = wid & 1;          // 0..1 col half

    // ---- A fragments: 64 rows (this wave's wm half), in registers ----
    const char* abase = (const char*)rn + (size_t)(bi * TILE + wm * 64 + l15) * 256;
    bf16x8 af[4][4];
    #pragma unroll
    for (int mf = 0; mf < 4; ++mf)
        #pragma unroll
        for (int kk = 0; kk < 4; ++kk)
            af[mf][kk] = *(const bf16x8*)(abase + mf * 16 * 256 + kk * 64 + kg * 16);

    // ---- stage tile 0 (pre-swizzled global source, linear LDS dest) ----
    {
        const char* gbase = (const char*)rn + (size_t)(g * TPB) * TILE * 256;
        #pragma unroll
        for (int j = 0; j < 8; ++j) {
            int cs  = (wid * 8 + j) * 64 + lane;
            int gsc = cs ^ ((cs >> 4) & 7);
            __builtin_amdgcn_global_load_lds((glb_u32*)(gbase + (size_t)gsc * 16),
                                             (lds_u32*)(&Bt[0][0] + (wid * 8 + j) * 512),
                                             16, 0, 0);
        }
    }
    __syncthreads();

    float rsum[4][4] = {};
    const int bjp = (bi + 32) & 63;

    for (int t = 0; t < TPB; ++t) {
        const int bj = g * TPB + t;

        // prefetch next tile into the other buffer (completes before the
        // end-of-iteration __syncthreads drains vmcnt)
        if (t + 1 < TPB) {
            const char* gbase = (const char*)rn + (size_t)(bj + 1) * TILE * 256;
            ushort* dst = &Bt[(t + 1) & 1][0];
            #pragma unroll
            for (int j = 0; j < 8; ++j) {
                int cs  = (wid * 8 + j) * 64 + lane;
                int gsc = cs ^ ((cs >> 4) & 7);
                __builtin_amdgcn_global_load_lds((glb_u32*)(gbase + (size_t)gsc * 16),
                                                 (lds_u32*)(dst + (wid * 8 + j) * 512),
                                                 16, 0, 0);
            }
        }

        // ---- MFMA: 64 rows x 64 cols per wave, K=128 ----
        f32x4 acc[4][4] = {};
        const char* Bb = (const char*)&Bt[t & 1][0];
        #pragma unroll
        for (int kk = 0; kk < 4; ++kk) {
            const int kb = kk * 64 + kg * 16;
            bf16x8 bfr[4];
            #pragma unroll
            for (int nf = 0; nf < 4; ++nf) {
                int cR = wn * 64 + nf * 16 + l15;
                int o = cR * 256 + kb;
                bfr[nf] = *(const bf16x8*)(Bb + (o ^ ((cR & 7) << 4)));
            }
            #pragma unroll
            for (int mf = 0; mf < 4; ++mf)
                #pragma unroll
                for (int nf = 0; nf < 4; ++nf)
                    acc[mf][nf] = __builtin_amdgcn_mfma_f32_16x16x32_bf16(
                        af[mf][kk], bfr[nf], acc[mf][nf], 0, 0, 0);
        }

        // ---- epilogue (register-only): exp + rsum accumulate ----
        const bool diag = (bj == bi);
        const bool posb = (bj == bjp) && (wm == wn);
        const bool dglb = diag && (wm == wn);
        #pragma unroll
        for (int mf = 0; mf < 4; ++mf) {
            #pragma unroll
            for (int nf = 0; nf < 4; ++nf) {
                #pragma unroll
                for (int reg = 0; reg < 4; ++reg) {
                    float s = acc[mf][nf][reg];
                    bool hit = (mf == nf) && ((kg * 4 + reg) == l15);
                    if (posb && hit)
                        pos[bi * TILE + wm * 64 + mf * 16 + l15] = s;
                    float p = __expf(s * INV_TAU);
                    if (dglb && hit) p = 0.0f;
                    rsum[mf][reg] += p;
                }
            }
        }

        __syncthreads();   // drains vmcnt (stage t+1 done) + protects buffers
    }

    // ---- row-sum reduce: across l15 lanes, then across wn via LDS ----
    #pragma unroll
    for (int mf = 0; mf < 4; ++mf)
        #pragma unroll
        for (int reg = 0; reg < 4; ++reg) {
            float v = rsum[mf][reg];
            v += __shfl_xor(v, 1);
            v += __shfl_xor(v, 2);
            v += __shfl_xor(v, 4);
            v += __shfl_xor(v, 8);
            rsum[mf][reg] = v;   // valid on l15==0 lanes
        }

    float* red = (float*)&Bt[0][0];
    if (wn == 1 && l15 == 0) {
        #pragma unroll
        for (int mf = 0; mf < 4; ++mf)
            #pragma unroll
            for (int reg = 0; reg < 4; ++reg)
                red[wm * 64 + mf * 16 + kg * 4 + reg] = rsum[mf][reg];
    }
    __syncthreads();
    if (wn == 0 && l15 == 0) {
        #pragma unroll
        for (int mf = 0; mf < 4; ++mf)
            #pragma unroll
            for (int reg = 0; reg < 4; ++reg) {
                int lr = wm * 64 + mf * 16 + kg * 4 + reg;
                atomicAdd(&sumexp[bi * TILE + lr], rsum[mf][reg] + red[lr]);
            }
    }
}

// ---------------- Kernel 3: final scalar reduction ----------------
__global__ __launch_bounds__(1024)
void reduce_kernel(const float* __restrict__ sumexp,
                   const float* __restrict__ pos,
                   float* __restrict__ out) {
    int tid = threadIdx.x;  // 1024; 8 elements each
    int base = tid * 8;
    float ce = 0.f, pt = 0.f;
    #pragma unroll
    for (int h = 0; h < 2; ++h) {
        float4 se4 = *(const float4*)(sumexp + base + h * 4);
        float4 p4  = *(const float4*)(pos + base + h * 4);
        const float* se = (const float*)&se4;
        const float* pp = (const float*)&p4;
        #pragma unroll
        for (int q = 0; q < 4; ++q) {
            ce += __logf(se[q]) - pp[q] * INV_TAU;
            pt += __expf(pp[q] * INV_TAU) / se[q];
        }
    }
    #pragma unroll
    for (int off = 32; off; off >>= 1) {
        ce += __shfl_xor(ce, off);
        pt += __shfl_xor(pt, off);
    }
    __shared__ float lce[16], lpt[16];
    if ((tid & 63) == 0) { lce[tid >> 6] = ce; lpt[tid >> 6] = pt; }
    __syncthreads();
    if (tid == 0) {
        float CE = 0.f, PT = 0.f;
        #pragma unroll
        for (int w = 0; w < 16; ++w) { CE += lce[w]; PT += lpt[w]; }
        float loss = CE / (float)NSZ + 1.0f
                   - PT * ((float)BSZ / ((float)NSZ * (float)(NSZ - 1)));
        out[0] = loss;
    }
}

extern "C" void kernel_launch(void* const* d_in, const int* in_sizes, int n_in,
                              void* d_out, int out_size, void* d_ws, size_t ws_size,
                              hipStream_t stream) {
    const float* zis = (const float*)d_in[0];
    const float* zjs = (const float*)d_in[1];
    float* out = (float*)d_out;

    char* ws = (char*)d_ws;
    __hip_bfloat16* rn = (__hip_bfloat16*)ws;                 // 2 MB
    float* sumexp = (float*)(ws + 2 * 1024 * 1024);           // 32 KB
    float* pos    = (float*)(ws + 2 * 1024 * 1024 + 32768);   // 32 KB

    hipMemsetAsync(sumexp, 0, NSZ * sizeof(float), stream);

    norm_kernel<<<NSZ / 4, 256, 0, stream>>>(zis, zjs, rn);

    dim3 grid(GROUPS, 64);
    sim_lse_kernel<<<grid, 256, 0, stream>>>(rn, sumexp, pos);

    reduce_kernel<<<1, 1024, 0, stream>>>(sumexp, pos, out);
}

// Round 5
// 40.940 us; speedup vs baseline: 4.7775x; 1.0636x over previous
//
#include <hip/hip_runtime.h>
#include <hip/hip_bf16.h>

#define BSZ 4096
#define NSZ 8192
#define DD  128
#define TILE 128
#define INV_TAU 10.0f
#define GROUPS 8
#define TPB 8     // col-tiles per block

typedef __attribute__((ext_vector_type(8))) short bf16x8;
typedef __attribute__((ext_vector_type(4))) float f32x4;

typedef __attribute__((address_space(3))) unsigned int lds_u32;
typedef const __attribute__((address_space(1))) unsigned int glb_u32;

// ---------------- Kernel 1: normalize rows of reps=[zjs; zis] -> bf16 ----------------
__global__ __launch_bounds__(256)
void norm_kernel(const float* __restrict__ zis,
                 const float* __restrict__ zjs,
                 __hip_bfloat16* __restrict__ rn) {
    const int row  = blockIdx.x * 4 + (threadIdx.x >> 6);
    const int lane = threadIdx.x & 63;
    const float* src = (row < BSZ) ? (zjs + (size_t)row * DD)
                                   : (zis + (size_t)(row - BSZ) * DD);
    float2 v = *(const float2*)(src + lane * 2);
    float ss = v.x * v.x + v.y * v.y;
    #pragma unroll
    for (int off = 32; off; off >>= 1) ss += __shfl_xor(ss, off);
    float inv = 1.0f / fmaxf(sqrtf(ss), 1e-8f);
    __hip_bfloat16 a = __float2bfloat16(v.x * inv);
    __hip_bfloat16 b = __float2bfloat16(v.y * inv);
    ushort2 pk;
    pk.x = *(const ushort*)&a;
    pk.y = *(const ushort*)&b;
    *(ushort2*)(rn + (size_t)row * DD + lane * 2) = pk;
}

// ---------------- Kernel 2: deep-loop fused sim GEMM + exp + row sums ----------------
// grid (GROUPS, 64): bi = blockIdx.y (row tile), g = blockIdx.x; block loops over
// bj = g*TPB .. g*TPB+TPB-1 with double-buffered LDS B staging (global_load_lds,
// pre-swizzled source). 256 threads = 4 waves in a 2x2 grid; each wave owns
// 64 rows x 64 cols. A-frags in registers for the whole block. Row-sums of
// exp(s/tau) accumulate in registers across all TPB tiles; block writes its
// 128 per-row partials to partials[g][...] -- no memset, no atomics.
__global__ __launch_bounds__(256, 2)
void sim_lse_kernel(const __hip_bfloat16* __restrict__ rn,
                    float* __restrict__ partials,
                    float* __restrict__ pos) {
    __shared__ ushort Bt[2][TILE * DD];   // 2 x 32 KB

    const int g   = blockIdx.x;
    const int bi  = blockIdx.y;
    const int tid = threadIdx.x;
    const int wid  = tid >> 6;
    const int lane = tid & 63;
    const int l15  = lane & 15;
    const int kg   = lane >> 4;        // 0..3
    const int wm   = wid >> 1;         // 0..1 row half
    const int wn   = wid & 1;          // 0..1 col half

    // ---- A fragments: 64 rows (this wave's wm half), in registers ----
    const char* abase = (const char*)rn + (size_t)(bi * TILE + wm * 64 + l15) * 256;
    bf16x8 af[4][4];
    #pragma unroll
    for (int mf = 0; mf < 4; ++mf)
        #pragma unroll
        for (int kk = 0; kk < 4; ++kk)
            af[mf][kk] = *(const bf16x8*)(abase + mf * 16 * 256 + kk * 64 + kg * 16);

    // ---- stage tile 0 (pre-swizzled global source, linear LDS dest) ----
    {
        const char* gbase = (const char*)rn + (size_t)(g * TPB) * TILE * 256;
        #pragma unroll
        for (int j = 0; j < 8; ++j) {
            int cs  = (wid * 8 + j) * 64 + lane;
            int gsc = cs ^ ((cs >> 4) & 7);
            __builtin_amdgcn_global_load_lds((glb_u32*)(gbase + (size_t)gsc * 16),
                                             (lds_u32*)(&Bt[0][0] + (wid * 8 + j) * 512),
                                             16, 0, 0);
        }
    }
    __syncthreads();

    float rsum[4][4] = {};
    const int bjp = (bi + 32) & 63;

    for (int t = 0; t < TPB; ++t) {
        const int bj = g * TPB + t;

        // prefetch next tile into the other buffer (completes before the
        // end-of-iteration __syncthreads drains vmcnt)
        if (t + 1 < TPB) {
            const char* gbase = (const char*)rn + (size_t)(bj + 1) * TILE * 256;
            ushort* dst = &Bt[(t + 1) & 1][0];
            #pragma unroll
            for (int j = 0; j < 8; ++j) {
                int cs  = (wid * 8 + j) * 64 + lane;
                int gsc = cs ^ ((cs >> 4) & 7);
                __builtin_amdgcn_global_load_lds((glb_u32*)(gbase + (size_t)gsc * 16),
                                                 (lds_u32*)(dst + (wid * 8 + j) * 512),
                                                 16, 0, 0);
            }
        }

        // ---- MFMA: 64 rows x 64 cols per wave, K=128 ----
        f32x4 acc[4][4] = {};
        const char* Bb = (const char*)&Bt[t & 1][0];
        #pragma unroll
        for (int kk = 0; kk < 4; ++kk) {
            const int kb = kk * 64 + kg * 16;
            bf16x8 bfr[4];
            #pragma unroll
            for (int nf = 0; nf < 4; ++nf) {
                int cR = wn * 64 + nf * 16 + l15;
                int o = cR * 256 + kb;
                bfr[nf] = *(const bf16x8*)(Bb + (o ^ ((cR & 7) << 4)));
            }
            #pragma unroll
            for (int mf = 0; mf < 4; ++mf)
                #pragma unroll
                for (int nf = 0; nf < 4; ++nf)
                    acc[mf][nf] = __builtin_amdgcn_mfma_f32_16x16x32_bf16(
                        af[mf][kk], bfr[nf], acc[mf][nf], 0, 0, 0);
        }

        // ---- epilogue (register-only): exp + rsum accumulate ----
        const bool diag = (bj == bi);
        const bool posb = (bj == bjp) && (wm == wn);
        const bool dglb = diag && (wm == wn);
        #pragma unroll
        for (int mf = 0; mf < 4; ++mf) {
            #pragma unroll
            for (int nf = 0; nf < 4; ++nf) {
                #pragma unroll
                for (int reg = 0; reg < 4; ++reg) {
                    float s = acc[mf][nf][reg];
                    bool hit = (mf == nf) && ((kg * 4 + reg) == l15);
                    if (posb && hit)
                        pos[bi * TILE + wm * 64 + mf * 16 + l15] = s;
                    float p = __expf(s * INV_TAU);
                    if (dglb && hit) p = 0.0f;
                    rsum[mf][reg] += p;
                }
            }
        }

        __syncthreads();   // drains vmcnt (stage t+1 done) + protects buffers
    }

    // ---- row-sum reduce: across l15 lanes, then across wn via LDS ----
    #pragma unroll
    for (int mf = 0; mf < 4; ++mf)
        #pragma unroll
        for (int reg = 0; reg < 4; ++reg) {
            float v = rsum[mf][reg];
            v += __shfl_xor(v, 1);
            v += __shfl_xor(v, 2);
            v += __shfl_xor(v, 4);
            v += __shfl_xor(v, 8);
            rsum[mf][reg] = v;   // valid on l15==0 lanes
        }

    float* red = (float*)&Bt[0][0];
    if (wn == 1 && l15 == 0) {
        #pragma unroll
        for (int mf = 0; mf < 4; ++mf)
            #pragma unroll
            for (int reg = 0; reg < 4; ++reg)
                red[wm * 64 + mf * 16 + kg * 4 + reg] = rsum[mf][reg];
    }
    __syncthreads();
    if (wn == 0 && l15 == 0) {
        #pragma unroll
        for (int mf = 0; mf < 4; ++mf)
            #pragma unroll
            for (int reg = 0; reg < 4; ++reg) {
                int lr = wm * 64 + mf * 16 + kg * 4 + reg;
                partials[(size_t)g * NSZ + bi * TILE + lr] = rsum[mf][reg] + red[lr];
            }
    }
}

// ---------------- Kernel 3: final scalar reduction ----------------
__global__ __launch_bounds__(1024)
void reduce_kernel(const float* __restrict__ partials,
                   const float* __restrict__ pos,
                   float* __restrict__ out) {
    int tid = threadIdx.x;  // 1024; 8 rows each
    int base = tid * 8;
    float se[8] = {0.f, 0.f, 0.f, 0.f, 0.f, 0.f, 0.f, 0.f};
    #pragma unroll
    for (int gr = 0; gr < GROUPS; ++gr) {
        const float* p = partials + (size_t)gr * NSZ + base;
        float4 a = *(const float4*)(p);
        float4 b = *(const float4*)(p + 4);
        se[0] += a.x; se[1] += a.y; se[2] += a.z; se[3] += a.w;
        se[4] += b.x; se[5] += b.y; se[6] += b.z; se[7] += b.w;
    }
    float ce = 0.f, pt = 0.f;
    #pragma unroll
    for (int h = 0; h < 2; ++h) {
        float4 p4 = *(const float4*)(pos + base + h * 4);
        const float* pp = (const float*)&p4;
        #pragma unroll
        for (int q = 0; q < 4; ++q) {
            float s = se[h * 4 + q];
            ce += __logf(s) - pp[q] * INV_TAU;
            pt += __expf(pp[q] * INV_TAU) / s;
        }
    }
    #pragma unroll
    for (int off = 32; off; off >>= 1) {
        ce += __shfl_xor(ce, off);
        pt += __shfl_xor(pt, off);
    }
    __shared__ float lce[16], lpt[16];
    if ((tid & 63) == 0) { lce[tid >> 6] = ce; lpt[tid >> 6] = pt; }
    __syncthreads();
    if (tid == 0) {
        float CE = 0.f, PT = 0.f;
        #pragma unroll
        for (int w = 0; w < 16; ++w) { CE += lce[w]; PT += lpt[w]; }
        float loss = CE / (float)NSZ + 1.0f
                   - PT * ((float)BSZ / ((float)NSZ * (float)(NSZ - 1)));
        out[0] = loss;
    }
}

extern "C" void kernel_launch(void* const* d_in, const int* in_sizes, int n_in,
                              void* d_out, int out_size, void* d_ws, size_t ws_size,
                              hipStream_t stream) {
    const float* zis = (const float*)d_in[0];
    const float* zjs = (const float*)d_in[1];
    float* out = (float*)d_out;

    char* ws = (char*)d_ws;
    __hip_bfloat16* rn = (__hip_bfloat16*)ws;                       // 2 MB
    float* partials = (float*)(ws + 2 * 1024 * 1024);               // 256 KB
    float* pos      = (float*)(ws + 2 * 1024 * 1024 + 256 * 1024);  // 32 KB

    norm_kernel<<<NSZ / 4, 256, 0, stream>>>(zis, zjs, rn);

    dim3 grid(GROUPS, 64);
    sim_lse_kernel<<<grid, 256, 0, stream>>>(rn, partials, pos);

    reduce_kernel<<<1, 1024, 0, stream>>>(partials, pos, out);
}